// Round 1
// baseline (934.355 us; speedup 1.0000x reference)
//
#include <hip/hip_runtime.h>
#include <cstdint>
#include <math.h>

#define B_SAMP 4096
#define D_DIM  128
#define N_ROWS 8192
#define NCLS   64

__device__ __forceinline__ float inv_temp() { return 1.0f / (0.07f + 1e-8f); }

__device__ __forceinline__ void jac(int a, int b, float& mv, float& mk) {
    int u = __popc(a & b);
    int l = __popc(a | b);
    mv = (float)u / ((float)l + 1e-8f);
    mk = (mv >= 0.3f) ? 1.0f : 0.0f;
}

// ---------------- K0: zero accumulators ----------------
__global__ void k_zero(float* F, int* count) {
    int t = threadIdx.x;
    for (int i = t; i < NCLS * D_DIM; i += 256) F[i] = 0.0f;
    if (t < NCLS) count[t] = 0;
}

// ---------------- K1: pack labels into 6-bit class + histogram ----------------
__global__ void k_pack(const int* __restrict__ labels, int* cls, int* count) {
    int b = blockIdx.x * 256 + threadIdx.x;
    if (b >= B_SAMP) return;
    int c = 0;
#pragma unroll
    for (int k = 0; k < 6; k++) c |= (labels[b * 6 + k] != 0) << k;
    cls[b] = c;
    atomicAdd(&count[c], 1);
}

// ---------------- K2: per-class feature sums F[c][d] (both views) ----------------
__global__ void k_feat(const float* __restrict__ feats, const int* __restrict__ cls, float* F) {
    __shared__ float loc[NCLS * D_DIM];
    for (int i = threadIdx.x; i < NCLS * D_DIM; i += 256) loc[i] = 0.0f;
    __syncthreads();
    const int total = B_SAMP * 2 * D_DIM;  // 1,048,576
    for (int e = blockIdx.x * blockDim.x + threadIdx.x; e < total; e += gridDim.x * blockDim.x) {
        int b = e >> 8;        // 256 floats per sample (2 views x 128)
        int d = e & 127;
        atomicAdd(&loc[cls[b] * D_DIM + d], feats[e]);
    }
    __syncthreads();
    for (int i = threadIdx.x; i < NCLS * D_DIM; i += 256) {
        float v = loc[i];
        if (v != 0.0f) atomicAdd(&F[i], v);
    }
}

// ---------------- K3: class tables G, Wm, W, diag terms ----------------
__global__ void k_tables(const float* __restrict__ F, const int* __restrict__ count,
                         float* G, float* WmC, float* WC, float* gdiag, float* mdiag) {
    int t = threadIdx.x;
    for (int idx = t; idx < NCLS * D_DIM; idx += 256) {
        int c = idx >> 7, d = idx & 127;
        float s = 0.0f;
        for (int c2 = 0; c2 < NCLS; c2++) {
            float mv, mk; jac(c, c2, mv, mk);
            s += mv * mk * F[c2 * D_DIM + d];
        }
        G[idx] = s;
    }
    if (t < NCLS) {
        float wm = 0.0f, w = 0.0f;
        for (int c2 = 0; c2 < NCLS; c2++) {
            float mv, mk; jac(t, c2, mv, mk);
            float cnt2 = 2.0f * (float)count[c2];   // each class appears in both views of columns
            wm += mv * mk * cnt2;
            w  += mk * cnt2;
        }
        float mv, mk; jac(t, t, mv, mk);
        WmC[t] = wm; WC[t] = w; gdiag[t] = mv * mk; mdiag[t] = mk;
    }
}

// ---------------- K4: per-row f.G and ||f||^2 (one wave per row) ----------------
__global__ void k_rowaux(const float* __restrict__ feats, const int* __restrict__ cls,
                         const float* __restrict__ G, float* fiG, float* nrm2) {
    int wid = (blockIdx.x * blockDim.x + threadIdx.x) >> 6;
    int lane = threadIdx.x & 63;
    if (wid >= N_ROWS) return;
    int b = wid & (B_SAMP - 1);
    int v = wid >> 12;
    const float* f = feats + (size_t)b * 256 + (size_t)v * 128;
    const float* g = G + (size_t)cls[b] * D_DIM;
    float2 fv = *(const float2*)(f + lane * 2);
    float2 gv = *(const float2*)(g + lane * 2);
    float dg = fv.x * gv.x + fv.y * gv.y;
    float nn = fv.x * fv.x + fv.y * fv.y;
#pragma unroll
    for (int o = 32; o; o >>= 1) { dg += __shfl_down(dg, o); nn += __shfl_down(nn, o); }
    if (lane == 0) { fiG[wid] = dg; nrm2[wid] = nn; }
}

// ---------------- K5: main N x N GEMM with fused online row-max / exp-sum ----------------
#define BR 32
#define BC 64
#define LDP 132  // padded row stride in floats (132*4 = 528 B, odd multiple of 16B)

__launch_bounds__(256)
__global__ void k_gemm(const float* __restrict__ feats, float* mrow, float* Srow) {
    __shared__ float As[BR * LDP];        // 16,896 B
    __shared__ float Bs[BC * LDP];        // 33,792 B
    __shared__ float2 red[BR * 16];       //  4,096 B
    const float invT = inv_temp();

    int tid = threadIdx.x;
    int tx = tid & 15;       // 16 col groups x 4 cols
    int ty = tid >> 4;       // 16 row groups x 2 rows
    int rowbase = blockIdx.x * BR;

    // stage A rows (32 x 128 floats = 1024 float4)
#pragma unroll
    for (int k = 0; k < 4; k++) {
        int i4 = tid + k * 256;
        int r = i4 >> 5, d4 = i4 & 31;
        int grow = rowbase + r;
        const float* src = feats + (size_t)(grow & (B_SAMP - 1)) * 256 + (size_t)(grow >> 12) * 128;
        *(float4*)&As[r * LDP + d4 * 4] = *(const float4*)(src + d4 * 4);
    }
    __syncthreads();

    float m[2] = {-INFINITY, -INFINITY};
    float s[2] = {0.0f, 0.0f};

    for (int tile = 0; tile < N_ROWS / BC; ++tile) {
        // stage B cols (64 x 128 floats = 2048 float4)
#pragma unroll
        for (int k = 0; k < 8; k++) {
            int i4 = tid + k * 256;
            int cc = i4 >> 5, d4 = i4 & 31;
            int gcol = tile * BC + cc;
            const float* src = feats + (size_t)(gcol & (B_SAMP - 1)) * 256 + (size_t)(gcol >> 12) * 128;
            *(float4*)&Bs[cc * LDP + d4 * 4] = *(const float4*)(src + d4 * 4);
        }
        __syncthreads();

        float acc[2][4] = {};
#pragma unroll 8
        for (int d4 = 0; d4 < 32; ++d4) {
            float4 a0 = *(float4*)&As[(ty * 2 + 0) * LDP + d4 * 4];
            float4 a1 = *(float4*)&As[(ty * 2 + 1) * LDP + d4 * 4];
            float4 b0 = *(float4*)&Bs[(tx * 4 + 0) * LDP + d4 * 4];
            float4 b1 = *(float4*)&Bs[(tx * 4 + 1) * LDP + d4 * 4];
            float4 b2 = *(float4*)&Bs[(tx * 4 + 2) * LDP + d4 * 4];
            float4 b3 = *(float4*)&Bs[(tx * 4 + 3) * LDP + d4 * 4];
            acc[0][0] += a0.x * b0.x + a0.y * b0.y + a0.z * b0.z + a0.w * b0.w;
            acc[0][1] += a0.x * b1.x + a0.y * b1.y + a0.z * b1.z + a0.w * b1.w;
            acc[0][2] += a0.x * b2.x + a0.y * b2.y + a0.z * b2.z + a0.w * b2.w;
            acc[0][3] += a0.x * b3.x + a0.y * b3.y + a0.z * b3.z + a0.w * b3.w;
            acc[1][0] += a1.x * b0.x + a1.y * b0.y + a1.z * b0.z + a1.w * b0.w;
            acc[1][1] += a1.x * b1.x + a1.y * b1.y + a1.z * b1.z + a1.w * b1.w;
            acc[1][2] += a1.x * b2.x + a1.y * b2.y + a1.z * b2.z + a1.w * b2.w;
            acc[1][3] += a1.x * b3.x + a1.y * b3.y + a1.z * b3.z + a1.w * b3.w;
        }

        // fused per-element online max / exp-sum (diag in max, excluded from sum)
#pragma unroll
        for (int i = 0; i < 2; i++) {
            int grow = rowbase + ty * 2 + i;
#pragma unroll
            for (int j = 0; j < 4; j++) {
                int gcol = tile * BC + tx * 4 + j;
                float dot = acc[i][j];
                if (dot > m[i]) {
                    s[i] *= __expf((m[i] - dot) * invT);
                    m[i] = dot;
                    if (gcol != grow) s[i] += 1.0f;
                } else if (gcol != grow) {
                    s[i] += __expf((dot - m[i]) * invT);
                }
            }
        }
        __syncthreads();
    }

    // combine the 16 col-group partials per row
#pragma unroll
    for (int i = 0; i < 2; i++) red[(ty * 2 + i) * 16 + tx] = make_float2(m[i], s[i]);
    __syncthreads();
    if (tid < BR) {
        float mm = -INFINITY, ss = 0.0f;
        const float2* rr = &red[tid * 16];
#pragma unroll
        for (int k = 0; k < 16; k++) mm = fmaxf(mm, rr[k].x);
#pragma unroll
        for (int k = 0; k < 16; k++) ss += rr[k].y * __expf((rr[k].x - mm) * invT);
        int grow = rowbase + tid;
        mrow[grow] = mm * invT;   // logit-scale max
        Srow[grow] = ss;
    }
}

// ---------------- K6: per-row loss + per-block partial sums ----------------
__global__ void k_final(const int* __restrict__ cls, const float* __restrict__ mrow,
                        const float* __restrict__ Srow, const float* __restrict__ fiG,
                        const float* __restrict__ nrm2, const float* __restrict__ WmC,
                        const float* __restrict__ WC, const float* __restrict__ gdiag,
                        const float* __restrict__ mdiag, float* partial) {
    const float invT = inv_temp();
    int n = blockIdx.x * 256 + threadIdx.x;
    int c = cls[n & (B_SAMP - 1)];
    float wm = WmC[c] - gdiag[c];
    float w  = WC[c]  - mdiag[c];
    float swl = (fiG[n] - gdiag[c] * nrm2[n]) * invT;
    float lp = swl - wm * mrow[n] - wm * logf(Srow[n] + 1e-8f);
    float loss = -lp / (w + 1e-8f);

    // reduce within block
#pragma unroll
    for (int o = 32; o; o >>= 1) loss += __shfl_down(loss, o);
    __shared__ float ws4[4];
    if ((threadIdx.x & 63) == 0) ws4[threadIdx.x >> 6] = loss;
    __syncthreads();
    if (threadIdx.x == 0) partial[blockIdx.x] = ws4[0] + ws4[1] + ws4[2] + ws4[3];
}

// ---------------- K7: final deterministic reduce ----------------
__global__ void k_out(const float* __restrict__ partial, float* out) {
    if (threadIdx.x == 0) {
        float s = 0.0f;
        for (int k = 0; k < 32; k++) s += partial[k];
        out[0] = s / (float)N_ROWS;
    }
}

extern "C" void kernel_launch(void* const* d_in, const int* in_sizes, int n_in,
                              void* d_out, int out_size, void* d_ws, size_t ws_size,
                              hipStream_t stream) {
    const float* feats  = (const float*)d_in[0];
    const int*   labels = (const int*)d_in[1];
    float* out = (float*)d_out;

    // workspace layout (all 4-byte aligned)
    char* ws = (char*)d_ws;
    int*   cls    = (int*)ws;                 ws += B_SAMP * 4;          // 16384
    int*   count  = (int*)ws;                 ws += NCLS * 4;            // 256
    float* F      = (float*)ws;               ws += NCLS * D_DIM * 4;    // 32768
    float* G      = (float*)ws;               ws += NCLS * D_DIM * 4;    // 32768
    float* WmC    = (float*)ws;               ws += NCLS * 4;
    float* WC     = (float*)ws;               ws += NCLS * 4;
    float* gdiag  = (float*)ws;               ws += NCLS * 4;
    float* mdiag  = (float*)ws;               ws += NCLS * 4;
    float* fiG    = (float*)ws;               ws += N_ROWS * 4;
    float* nrm2   = (float*)ws;               ws += N_ROWS * 4;
    float* mrow   = (float*)ws;               ws += N_ROWS * 4;
    float* Srow   = (float*)ws;               ws += N_ROWS * 4;
    float* partial= (float*)ws;               ws += 32 * 4;

    k_zero  <<<1, 256, 0, stream>>>(F, count);
    k_pack  <<<B_SAMP / 256, 256, 0, stream>>>(labels, cls, count);
    k_feat  <<<32, 256, 0, stream>>>(feats, cls, F);
    k_tables<<<1, 256, 0, stream>>>(F, count, G, WmC, WC, gdiag, mdiag);
    k_rowaux<<<(N_ROWS * 64) / 256, 256, 0, stream>>>(feats, cls, G, fiG, nrm2);
    k_gemm  <<<N_ROWS / BR, 256, 0, stream>>>(feats, mrow, Srow);
    k_final <<<N_ROWS / 256, 256, 0, stream>>>(cls, mrow, Srow, fiG, nrm2, WmC, WC, gdiag, mdiag, partial);
    k_out   <<<1, 64, 0, stream>>>(partial, out);
}

// Round 2
// 101.194 us; speedup vs baseline: 9.2333x; 9.2333x over previous
//
#include <hip/hip_runtime.h>
#include <cstdint>
#include <math.h>

#define B_SAMP 4096
#define D_DIM  128
#define N_ROWS 8192
#define NCLS   64
#define NCHUNK 16
#define CCHUNK 512
#define TC     64
#define NTILE  (CCHUNK / TC)
#define THR_DOT 2.1f

typedef __attribute__((ext_vector_type(8))) short short8;
typedef __attribute__((ext_vector_type(4))) float f32x4;

__device__ __forceinline__ float inv_temp() { return 1.0f / (0.07f + 1e-8f); }

__device__ __forceinline__ void jac(int a, int b, float& mv, float& mk) {
    int u = __popc(a & b);
    int l = __popc(a | b);
    mv = (float)u / ((float)l + 1e-8f);
    mk = (mv >= 0.3f) ? 1.0f : 0.0f;
}

// ---------------- K0: zero accumulators ----------------
__global__ void k_zero(float* F, int* count) {
    int t = threadIdx.x;
    for (int i = t; i < NCLS * D_DIM; i += 256) F[i] = 0.0f;
    if (t < NCLS) count[t] = 0;
}

// ---------------- K1: pack labels into 6-bit class + histogram ----------------
__global__ void k_pack(const int* __restrict__ labels, int* cls, int* count) {
    int b = blockIdx.x * 256 + threadIdx.x;
    if (b >= B_SAMP) return;
    int c = 0;
#pragma unroll
    for (int k = 0; k < 6; k++) c |= (labels[b * 6 + k] != 0) << k;
    cls[b] = c;
    atomicAdd(&count[c], 1);
}

// ---------------- K_cast: fp32 features -> bf16 contrast-ordered [8192][128] ----------------
__global__ void k_cast(const float* __restrict__ feats, ushort* __restrict__ fb) {
    int i = blockIdx.x * 256 + threadIdx.x;   // 262144 threads, 4 floats each
    int n = i >> 5;
    int d4 = (i & 31) * 4;
    const float* src = feats + (size_t)(n & (B_SAMP - 1)) * 256 + (size_t)(n >> 12) * 128 + d4;
    float4 v = *(const float4*)src;
    ushort4 h;
    uint u;
    u = __float_as_uint(v.x); u += 0x7FFF + ((u >> 16) & 1); h.x = (ushort)(u >> 16);
    u = __float_as_uint(v.y); u += 0x7FFF + ((u >> 16) & 1); h.y = (ushort)(u >> 16);
    u = __float_as_uint(v.z); u += 0x7FFF + ((u >> 16) & 1); h.z = (ushort)(u >> 16);
    u = __float_as_uint(v.w); u += 0x7FFF + ((u >> 16) & 1); h.w = (ushort)(u >> 16);
    *(ushort4*)&fb[(size_t)n * D_DIM + d4] = h;
}

// ---------------- K2: per-class feature sums F[c][d] (both views) ----------------
__global__ void k_feat(const float* __restrict__ feats, const int* __restrict__ cls, float* F) {
    __shared__ float loc[NCLS * D_DIM];
    for (int i = threadIdx.x; i < NCLS * D_DIM; i += 256) loc[i] = 0.0f;
    __syncthreads();
    const int total = B_SAMP * 2 * D_DIM;
    for (int e = blockIdx.x * blockDim.x + threadIdx.x; e < total; e += gridDim.x * blockDim.x) {
        int b = e >> 8;
        int d = e & 127;
        atomicAdd(&loc[cls[b] * D_DIM + d], feats[e]);
    }
    __syncthreads();
    for (int i = threadIdx.x; i < NCLS * D_DIM; i += 256) {
        float v = loc[i];
        if (v != 0.0f) atomicAdd(&F[i], v);
    }
}

// ---------------- K3: class tables G, Wm, W, diag terms (64 blocks x 128 thr) ----------------
__global__ void k_tables(const float* __restrict__ F, const int* __restrict__ count,
                         float* G, float* WmC, float* WC, float* gdiag, float* mdiag) {
    int c = blockIdx.x;
    int d = threadIdx.x;
    float sum = 0.0f;
    for (int c2 = 0; c2 < NCLS; c2++) {
        float mv, mk; jac(c, c2, mv, mk);
        sum += mv * mk * F[c2 * D_DIM + d];
    }
    G[c * D_DIM + d] = sum;
    if (d == 0) {
        float wm = 0.0f, wv = 0.0f;
        for (int c2 = 0; c2 < NCLS; c2++) {
            float mv, mk; jac(c, c2, mv, mk);
            float cnt2 = 2.0f * (float)count[c2];
            wm += mv * mk * cnt2;
            wv += mk * cnt2;
        }
        float mv, mk; jac(c, c, mv, mk);
        WmC[c] = wm; WC[c] = wv; gdiag[c] = mv * mk; mdiag[c] = mk;
    }
}

// ---------------- K4: per-row f.G and ||f||^2 (one wave per row, fp32) ----------------
__global__ void k_rowaux(const float* __restrict__ feats, const int* __restrict__ cls,
                         const float* __restrict__ G, float* fiG, float* nrm2) {
    int wid = (blockIdx.x * blockDim.x + threadIdx.x) >> 6;
    int lane = threadIdx.x & 63;
    if (wid >= N_ROWS) return;
    int b = wid & (B_SAMP - 1);
    int v = wid >> 12;
    const float* f = feats + (size_t)b * 256 + (size_t)v * 128;
    const float* g = G + (size_t)cls[b] * D_DIM;
    float2 fv = *(const float2*)(f + lane * 2);
    float2 gv = *(const float2*)(g + lane * 2);
    float dg = fv.x * gv.x + fv.y * gv.y;
    float nn = fv.x * fv.x + fv.y * fv.y;
#pragma unroll
    for (int o = 32; o; o >>= 1) { dg += __shfl_down(dg, o); nn += __shfl_down(nn, o); }
    if (lane == 0) { fiG[wid] = dg; nrm2[wid] = nn; }
}

// ---------------- K5: bf16 MFMA GEMM with fused online row-max / exp-sum ----------------
// grid: 512 blocks = 32 row-blocks (256 rows) x 16 col-chunks (512 cols).
// block: 256 thr = 4 waves; wave owns 64 rows, A-frags in registers (16 x short8).
// B tile (64 cols x 128 k bf16) double-buffered in LDS, XOR-swizzled (T2),
// staged via global_load_lds width=16 with pre-swizzled global source (rule #21).
__launch_bounds__(256, 2)
__global__ void k_gemm2(const ushort* __restrict__ fb, float* __restrict__ pm, float* __restrict__ ps) {
    __shared__ ushort Bs[2][TC * D_DIM];   // 2 x 16 KiB
    const float invT = inv_temp();
    int tid = threadIdx.x;
    int lane = tid & 63, w = tid >> 6;
    int rowBlk = blockIdx.x & 31;
    int chunk  = blockIdx.x >> 5;
    int rowbase = rowBlk * 256 + w * 64;
    int colChunk = chunk * CCHUNK;

    // A fragments: lane holds row = rowbase + rf*16 + (lane&15), k = kk*32 + (lane>>4)*8 .. +8
    short8 a[4][4];
    {
        int r = lane & 15, kb = (lane >> 4) * 8;
#pragma unroll
        for (int rf = 0; rf < 4; rf++)
#pragma unroll
            for (int kk = 0; kk < 4; kk++)
                a[rf][kk] = *(const short8*)&fb[(size_t)(rowbase + rf * 16 + r) * D_DIM + kk * 32 + kb];
    }

    // staging source offsets (ushort units), pre-swizzled: LDS[col][chunk] = glob[col][chunk ^ (col&7)]
    int sOff[4];
#pragma unroll
    for (int j = 0; j < 4; j++) {
        int c = (w * 4 + j) * 4 + (lane >> 4);
        int sw = (lane & 15) ^ (c & 7);
        sOff[j] = c * D_DIM + sw * 8;
    }

    float m[16], s[16];
#pragma unroll
    for (int i = 0; i < 16; i++) { m[i] = -INFINITY; s[i] = 0.0f; }

    // prologue: stage tile 0 -> buf 0
#pragma unroll
    for (int j = 0; j < 4; j++) {
        const ushort* g = fb + (size_t)colChunk * D_DIM + sOff[j];
        __builtin_amdgcn_global_load_lds((const __attribute__((address_space(1))) void*)g,
            (__attribute__((address_space(3))) void*)&Bs[0][(w * 4 + j) * 512], 16, 0, 0);
    }
    __syncthreads();

    for (int t = 0; t < NTILE; t++) {
        int cur = t & 1;
        if (t + 1 < NTILE) {
#pragma unroll
            for (int j = 0; j < 4; j++) {
                const ushort* g = fb + (size_t)(colChunk + (t + 1) * TC) * D_DIM + sOff[j];
                __builtin_amdgcn_global_load_lds((const __attribute__((address_space(1))) void*)g,
                    (__attribute__((address_space(3))) void*)&Bs[cur ^ 1][(w * 4 + j) * 512], 16, 0, 0);
            }
        }

        f32x4 acc[4][4];
#pragma unroll
        for (int rf = 0; rf < 4; rf++)
#pragma unroll
            for (int cf = 0; cf < 4; cf++)
                acc[rf][cf] = (f32x4){0.f, 0.f, 0.f, 0.f};

#pragma unroll
        for (int cf = 0; cf < 4; cf++) {
            int col = cf * 16 + (lane & 15);
            short8 b[4];
#pragma unroll
            for (int kk = 0; kk < 4; kk++) {
                int sw = (kk * 4 + (lane >> 4)) ^ (lane & 7);
                b[kk] = *(const short8*)&Bs[cur][col * D_DIM + sw * 8];
            }
#pragma unroll
            for (int rf = 0; rf < 4; rf++)
#pragma unroll
                for (int kk = 0; kk < 4; kk++)
                    acc[rf][cf] = __builtin_amdgcn_mfma_f32_16x16x32_bf16(a[rf][kk], b[kk], acc[rf][cf], 0, 0, 0);
        }

        // fused online max / exp-sum; skip-threshold: dropped terms < e^-30 each
        int tileCol = colChunk + t * TC + (lane & 15);
#pragma unroll
        for (int rf = 0; rf < 4; rf++) {
#pragma unroll
            for (int r = 0; r < 4; r++) {
                float v0 = acc[rf][0][r], v1 = acc[rf][1][r], v2 = acc[rf][2][r], v3 = acc[rf][3][r];
                float tmax = fmaxf(fmaxf(v0, v1), fmaxf(v2, v3));
                int idx = rf * 4 + r;
                if (tmax > m[idx] - THR_DOT) {
                    int grow = rowbase + rf * 16 + (lane >> 4) * 4 + r;
                    float nm = fmaxf(m[idx], tmax);
                    float sc = __expf((m[idx] - nm) * invT);
                    float e0 = (tileCol      == grow) ? 0.f : __expf((v0 - nm) * invT);
                    float e1 = (tileCol + 16 == grow) ? 0.f : __expf((v1 - nm) * invT);
                    float e2 = (tileCol + 32 == grow) ? 0.f : __expf((v2 - nm) * invT);
                    float e3 = (tileCol + 48 == grow) ? 0.f : __expf((v3 - nm) * invT);
                    s[idx] = s[idx] * sc + ((e0 + e1) + (e2 + e3));
                    m[idx] = nm;
                }
            }
        }
        __syncthreads();
    }

    // merge the 16 col-slot partials (xor over low 4 lane bits)
#pragma unroll
    for (int i = 0; i < 16; i++) {
#pragma unroll
        for (int off = 1; off < 16; off <<= 1) {
            float om = __shfl_xor(m[i], off);
            float os = __shfl_xor(s[i], off);
            float nm = fmaxf(m[i], om);
            s[i] = s[i] * __expf((m[i] - nm) * invT) + os * __expf((om - nm) * invT);
            m[i] = nm;
        }
    }
    if ((lane & 15) == 0) {
#pragma unroll
        for (int rf = 0; rf < 4; rf++)
#pragma unroll
            for (int r = 0; r < 4; r++) {
                int grow = rowbase + rf * 16 + (lane >> 4) * 4 + r;
                pm[chunk * N_ROWS + grow] = m[rf * 4 + r];
                ps[chunk * N_ROWS + grow] = s[rf * 4 + r];
            }
    }
}

// ---------------- K_combine: merge 16 chunk partials per row ----------------
__global__ void k_combine(const float* __restrict__ pm, const float* __restrict__ ps,
                          float* __restrict__ mrow, float* __restrict__ Srow) {
    const float invT = inv_temp();
    int rowI = blockIdx.x * 256 + threadIdx.x;
    float m = pm[rowI], s = ps[rowI];
#pragma unroll
    for (int ch = 1; ch < NCHUNK; ch++) {
        float om = pm[ch * N_ROWS + rowI], os = ps[ch * N_ROWS + rowI];
        float nm = fmaxf(m, om);
        s = s * __expf((m - nm) * invT) + os * __expf((om - nm) * invT);
        m = nm;
    }
    mrow[rowI] = m * invT;
    Srow[rowI] = s;
}

// ---------------- K6: per-row loss + per-block partial sums ----------------
__global__ void k_final(const int* __restrict__ cls, const float* __restrict__ mrow,
                        const float* __restrict__ Srow, const float* __restrict__ fiG,
                        const float* __restrict__ nrm2, const float* __restrict__ WmC,
                        const float* __restrict__ WC, const float* __restrict__ gdiag,
                        const float* __restrict__ mdiag, float* partial) {
    const float invT = inv_temp();
    int n = blockIdx.x * 256 + threadIdx.x;
    int c = cls[n & (B_SAMP - 1)];
    float wm = WmC[c] - gdiag[c];
    float w  = WC[c]  - mdiag[c];
    float swl = (fiG[n] - gdiag[c] * nrm2[n]) * invT;
    float lp = swl - wm * mrow[n] - wm * logf(Srow[n] + 1e-8f);
    float loss = -lp / (w + 1e-8f);
#pragma unroll
    for (int o = 32; o; o >>= 1) loss += __shfl_down(loss, o);
    __shared__ float ws4[4];
    if ((threadIdx.x & 63) == 0) ws4[threadIdx.x >> 6] = loss;
    __syncthreads();
    if (threadIdx.x == 0) partial[blockIdx.x] = ws4[0] + ws4[1] + ws4[2] + ws4[3];
}

// ---------------- K7: final deterministic reduce ----------------
__global__ void k_out(const float* __restrict__ partial, float* out) {
    if (threadIdx.x == 0) {
        float s = 0.0f;
        for (int k = 0; k < 32; k++) s += partial[k];
        out[0] = s / (float)N_ROWS;
    }
}

extern "C" void kernel_launch(void* const* d_in, const int* in_sizes, int n_in,
                              void* d_out, int out_size, void* d_ws, size_t ws_size,
                              hipStream_t stream) {
    const float* feats  = (const float*)d_in[0];
    const int*   labels = (const int*)d_in[1];
    float* out = (float*)d_out;

    char* ws = (char*)d_ws;
    ushort* fb    = (ushort*)ws;              ws += (size_t)N_ROWS * D_DIM * 2;      // 2 MiB
    float* pm     = (float*)ws;               ws += (size_t)NCHUNK * N_ROWS * 4;     // 512 KiB
    float* ps     = (float*)ws;               ws += (size_t)NCHUNK * N_ROWS * 4;     // 512 KiB
    int*   cls    = (int*)ws;                 ws += B_SAMP * 4;
    int*   count  = (int*)ws;                 ws += NCLS * 4;
    float* F      = (float*)ws;               ws += NCLS * D_DIM * 4;
    float* G      = (float*)ws;               ws += NCLS * D_DIM * 4;
    float* WmC    = (float*)ws;               ws += NCLS * 4;
    float* WC     = (float*)ws;               ws += NCLS * 4;
    float* gdiag  = (float*)ws;               ws += NCLS * 4;
    float* mdiag  = (float*)ws;               ws += NCLS * 4;
    float* fiG    = (float*)ws;               ws += N_ROWS * 4;
    float* nrm2   = (float*)ws;               ws += N_ROWS * 4;
    float* mrow   = (float*)ws;               ws += N_ROWS * 4;
    float* Srow   = (float*)ws;               ws += N_ROWS * 4;
    float* partial= (float*)ws;               ws += 32 * 4;

    k_zero   <<<1, 256, 0, stream>>>(F, count);
    k_pack   <<<B_SAMP / 256, 256, 0, stream>>>(labels, cls, count);
    k_cast   <<<1024, 256, 0, stream>>>(feats, fb);
    k_feat   <<<64, 256, 0, stream>>>(feats, cls, F);
    k_tables <<<NCLS, 128, 0, stream>>>(F, count, G, WmC, WC, gdiag, mdiag);
    k_rowaux <<<(N_ROWS * 64) / 256, 256, 0, stream>>>(feats, cls, G, fiG, nrm2);
    k_gemm2  <<<512, 256, 0, stream>>>(fb, pm, ps);
    k_combine<<<N_ROWS / 256, 256, 0, stream>>>(pm, ps, mrow, Srow);
    k_final  <<<N_ROWS / 256, 256, 0, stream>>>(cls, mrow, Srow, fiG, nrm2, WmC, WC, gdiag, mdiag, partial);
    k_out    <<<1, 64, 0, stream>>>(partial, out);
}

// Round 3
// 96.095 us; speedup vs baseline: 9.7232x; 1.0531x over previous
//
#include <hip/hip_runtime.h>
#include <cstdint>
#include <math.h>

#define B_SAMP 4096
#define D_DIM  128
#define N_ROWS 8192
#define NCLS   64
#define NCHUNK 16
#define CCHUNK 512
#define TC     64
#define NTILE  (CCHUNK / TC)
#define THR_DOT 2.1f

typedef __attribute__((ext_vector_type(8))) short short8;
typedef __attribute__((ext_vector_type(4))) float f32x4;

__device__ __forceinline__ float inv_temp() { return 1.0f / (0.07f + 1e-8f); }

__device__ __forceinline__ void jac(int a, int b, float& mv, float& mk) {
    int u = __popc(a & b);
    int l = __popc(a | b);
    mv = (float)u / ((float)l + 1e-8f);
    mk = (mv >= 0.3f) ? 1.0f : 0.0f;
}

__device__ __forceinline__ ushort bf16rne(float x) {
    uint u = __float_as_uint(x);
    u += 0x7FFF + ((u >> 16) & 1);
    return (ushort)(u >> 16);
}

// ---------------- K0: zero accumulators ----------------
__global__ void k_zero(float* F, int* count) {
    int t = threadIdx.x;
    for (int i = t; i < NCLS * D_DIM; i += 256) F[i] = 0.0f;
    if (t < NCLS) count[t] = 0;
}

// ---------------- K1: fused label-pack + bf16 cast + per-class sums ----------------
// grid 64 blocks x 256 thr; block b handles rows n0..n0+127 (one view).
__global__ void k_castfeat(const float* __restrict__ feats, const int* __restrict__ labels,
                           int* __restrict__ cls, int* __restrict__ count,
                           float* __restrict__ F, ushort* __restrict__ fb) {
    __shared__ float loc[NCLS * D_DIM];   // 32 KiB
    __shared__ int cls_loc[128];
    int b = blockIdx.x;
    int t = threadIdx.x;
    int n0 = b * 128;
    int s0 = n0 & (B_SAMP - 1);
    int view = n0 >> 12;
    for (int i = t; i < NCLS * D_DIM; i += 256) loc[i] = 0.0f;
    if (t < 128) {
        int c = 0;
#pragma unroll
        for (int k = 0; k < 6; k++) c |= (labels[(s0 + t) * 6 + k] != 0) << k;
        cls_loc[t] = c;
        if (view == 0) { cls[s0 + t] = c; atomicAdd(&count[c], 1); }
    }
    __syncthreads();
    // 128 rows x 128 d as float4 quads: 4096 quads, 16 iters/thread
    for (int q = t; q < 128 * 32; q += 256) {
        int r = q >> 5, d4 = (q & 31) * 4;
        const float* src = feats + (size_t)(s0 + r) * 256 + (size_t)view * 128 + d4;
        float4 v = *(const float4*)src;
        ushort4 h;
        h.x = bf16rne(v.x); h.y = bf16rne(v.y); h.z = bf16rne(v.z); h.w = bf16rne(v.w);
        *(ushort4*)&fb[(size_t)(n0 + r) * D_DIM + d4] = h;
        float* lrow = &loc[cls_loc[r] * D_DIM + d4];
        atomicAdd(&lrow[0], v.x); atomicAdd(&lrow[1], v.y);
        atomicAdd(&lrow[2], v.z); atomicAdd(&lrow[3], v.w);
    }
    __syncthreads();
    for (int i = t; i < NCLS * D_DIM; i += 256) {
        float v = loc[i];
        if (v != 0.0f) atomicAdd(&F[i], v);
    }
}

// ---------------- K2: class tables G, Wm, W, diag terms ----------------
__global__ void k_tables(const float* __restrict__ F, const int* __restrict__ count,
                         float* G, float* WmC, float* WC, float* gdiag, float* mdiag) {
    int c = blockIdx.x;
    int d = threadIdx.x;
    float sum = 0.0f;
    for (int c2 = 0; c2 < NCLS; c2++) {
        float mv, mk; jac(c, c2, mv, mk);
        sum += mv * mk * F[c2 * D_DIM + d];
    }
    G[c * D_DIM + d] = sum;
    if (d == 0) {
        float wm = 0.0f, wv = 0.0f;
        for (int c2 = 0; c2 < NCLS; c2++) {
            float mv, mk; jac(c, c2, mv, mk);
            float cnt2 = 2.0f * (float)count[c2];
            wm += mv * mk * cnt2;
            wv += mk * cnt2;
        }
        float mv, mk; jac(c, c, mv, mk);
        WmC[c] = wm; WC[c] = wv; gdiag[c] = mv * mk; mdiag[c] = mk;
    }
}

// ---------------- K3: bf16 MFMA GEMM with fused online row-max / exp-sum ----------------
// grid: 512 blocks = 32 row-blocks (256 rows) x 16 col-chunks (512 cols).
// block: 256 thr = 4 waves; wave owns 64 rows, A-frags in registers.
// launch_bounds(256,1): 512-VGPR cap -- round-2's (256,2) allocated only 96 VGPR
// and spilled the ~180-reg live set to scratch (41 us vs ~2 us MFMA floor).
__launch_bounds__(256, 1)
__global__ void k_gemm3(const ushort* __restrict__ fb, float* __restrict__ pm, float* __restrict__ ps) {
    __shared__ ushort Bs[2][TC * D_DIM];   // 2 x 16 KiB
    const float invT = inv_temp();
    int tid = threadIdx.x;
    int lane = tid & 63, w = tid >> 6;
    int rowBlk = blockIdx.x & 31;
    int chunk  = blockIdx.x >> 5;
    int rowbase = rowBlk * 256 + w * 64;
    int colChunk = chunk * CCHUNK;

    // A fragments: lane holds row = rowbase + rf*16 + (lane&15), k = kk*32 + (lane>>4)*8 .. +8
    short8 a[4][4];
    {
        int r = lane & 15, kb = (lane >> 4) * 8;
#pragma unroll
        for (int rf = 0; rf < 4; rf++)
#pragma unroll
            for (int kk = 0; kk < 4; kk++)
                a[rf][kk] = *(const short8*)&fb[(size_t)(rowbase + rf * 16 + r) * D_DIM + kk * 32 + kb];
    }

    // staging source offsets (ushort units), pre-swizzled: LDS[col][chunk] = glob[col][chunk ^ (col&7)]
    int sOff[4];
#pragma unroll
    for (int j = 0; j < 4; j++) {
        int c = (w * 4 + j) * 4 + (lane >> 4);
        int sw = (lane & 15) ^ (c & 7);
        sOff[j] = c * D_DIM + sw * 8;
    }

    float m[16], s[16];
#pragma unroll
    for (int i = 0; i < 16; i++) { m[i] = -INFINITY; s[i] = 0.0f; }

    // prologue: stage tile 0 -> buf 0
#pragma unroll
    for (int j = 0; j < 4; j++) {
        const ushort* g = fb + (size_t)colChunk * D_DIM + sOff[j];
        __builtin_amdgcn_global_load_lds((const __attribute__((address_space(1))) void*)g,
            (__attribute__((address_space(3))) void*)&Bs[0][(w * 4 + j) * 512], 16, 0, 0);
    }
    __syncthreads();

    for (int t = 0; t < NTILE; t++) {
        int cur = t & 1;
        if (t + 1 < NTILE) {
#pragma unroll
            for (int j = 0; j < 4; j++) {
                const ushort* g = fb + (size_t)(colChunk + (t + 1) * TC) * D_DIM + sOff[j];
                __builtin_amdgcn_global_load_lds((const __attribute__((address_space(1))) void*)g,
                    (__attribute__((address_space(3))) void*)&Bs[cur ^ 1][(w * 4 + j) * 512], 16, 0, 0);
            }
        }

        f32x4 acc[4][4];
#pragma unroll
        for (int rf = 0; rf < 4; rf++)
#pragma unroll
            for (int cf = 0; cf < 4; cf++)
                acc[rf][cf] = (f32x4){0.f, 0.f, 0.f, 0.f};

#pragma unroll
        for (int cf = 0; cf < 4; cf++) {
            int col = cf * 16 + (lane & 15);
            short8 b[4];
#pragma unroll
            for (int kk = 0; kk < 4; kk++) {
                int sw = (kk * 4 + (lane >> 4)) ^ (lane & 7);
                b[kk] = *(const short8*)&Bs[cur][col * D_DIM + sw * 8];
            }
#pragma unroll
            for (int rf = 0; rf < 4; rf++)
#pragma unroll
                for (int kk = 0; kk < 4; kk++)
                    acc[rf][cf] = __builtin_amdgcn_mfma_f32_16x16x32_bf16(a[rf][kk], b[kk], acc[rf][cf], 0, 0, 0);
        }

        // fused online max / exp-sum; skip-threshold: dropped terms < e^-30 each
        int tileCol = colChunk + t * TC + (lane & 15);
#pragma unroll
        for (int rf = 0; rf < 4; rf++) {
#pragma unroll
            for (int r = 0; r < 4; r++) {
                float v0 = acc[rf][0][r], v1 = acc[rf][1][r], v2 = acc[rf][2][r], v3 = acc[rf][3][r];
                float tmax = fmaxf(fmaxf(v0, v1), fmaxf(v2, v3));
                int idx = rf * 4 + r;
                if (tmax > m[idx] - THR_DOT) {
                    int grow = rowbase + rf * 16 + (lane >> 4) * 4 + r;
                    float nm = fmaxf(m[idx], tmax);
                    float sc = __expf((m[idx] - nm) * invT);
                    float e0 = (tileCol      == grow) ? 0.f : __expf((v0 - nm) * invT);
                    float e1 = (tileCol + 16 == grow) ? 0.f : __expf((v1 - nm) * invT);
                    float e2 = (tileCol + 32 == grow) ? 0.f : __expf((v2 - nm) * invT);
                    float e3 = (tileCol + 48 == grow) ? 0.f : __expf((v3 - nm) * invT);
                    s[idx] = s[idx] * sc + ((e0 + e1) + (e2 + e3));
                    m[idx] = nm;
                }
            }
        }
        __syncthreads();
    }

    // merge the 16 col-slot partials (xor over low 4 lane bits)
#pragma unroll
    for (int i = 0; i < 16; i++) {
#pragma unroll
        for (int off = 1; off < 16; off <<= 1) {
            float om = __shfl_xor(m[i], off);
            float os = __shfl_xor(s[i], off);
            float nm = fmaxf(m[i], om);
            s[i] = s[i] * __expf((m[i] - nm) * invT) + os * __expf((om - nm) * invT);
            m[i] = nm;
        }
    }
    if ((lane & 15) == 0) {
#pragma unroll
        for (int rf = 0; rf < 4; rf++)
#pragma unroll
            for (int r = 0; r < 4; r++) {
                int grow = rowbase + rf * 16 + (lane >> 4) * 4 + r;
                pm[chunk * N_ROWS + grow] = m[rf * 4 + r];
                ps[chunk * N_ROWS + grow] = s[rf * 4 + r];
            }
    }
}

// ---------------- K4: fused chunk-merge + f.G / ||f||^2 + per-row loss ----------------
// grid 2048 x 256: one wave per row.
__global__ void k_final2(const float* __restrict__ feats, const int* __restrict__ cls,
                         const float* __restrict__ G, const float* __restrict__ pm,
                         const float* __restrict__ ps, const float* __restrict__ WmC,
                         const float* __restrict__ WC, const float* __restrict__ gdiag,
                         const float* __restrict__ mdiag, float* __restrict__ partial) {
    const float invT = inv_temp();
    __shared__ float red[4];
    int tid = threadIdx.x;
    int lane = tid & 63, w = tid >> 6;
    int n = blockIdx.x * 4 + w;
    int samp = n & (B_SAMP - 1), view = n >> 12;
    int c = cls[samp];
    const float* f = feats + (size_t)samp * 256 + (size_t)view * 128;
    const float* g = G + (size_t)c * D_DIM;
    float2 fv = *(const float2*)(f + lane * 2);
    float2 gv = *(const float2*)(g + lane * 2);
    float dg = fv.x * gv.x + fv.y * gv.y;
    float nn = fv.x * fv.x + fv.y * fv.y;
#pragma unroll
    for (int o = 32; o; o >>= 1) { dg += __shfl_down(dg, o); nn += __shfl_down(nn, o); }
    dg = __shfl(dg, 0); nn = __shfl(nn, 0);

    float m = -INFINITY, s = 0.0f;
    if (lane < 16) { m = pm[lane * N_ROWS + n]; s = ps[lane * N_ROWS + n]; }
#pragma unroll
    for (int off = 8; off; off >>= 1) {
        float om = __shfl_xor(m, off);
        float os = __shfl_xor(s, off);
        float nm = fmaxf(m, om);
        s = s * __expf((m - nm) * invT) + os * __expf((om - nm) * invT);
        m = nm;
    }
    if (lane == 0) {
        float wm = WmC[c] - gdiag[c];
        float wv = WC[c] - mdiag[c];
        float swl = (dg - gdiag[c] * nn) * invT;
        float lp = swl - wm * (m * invT) - wm * logf(s + 1e-8f);
        red[w] = -lp / (wv + 1e-8f);
    }
    __syncthreads();
    if (tid == 0) partial[blockIdx.x] = (red[0] + red[1]) + (red[2] + red[3]);
}

// ---------------- K5: final deterministic reduce ----------------
__global__ void k_out(const float* __restrict__ partial, float* out) {
    __shared__ float red[4];
    int t = threadIdx.x;
    float s = 0.0f;
    for (int i = t; i < 2048; i += 256) s += partial[i];
#pragma unroll
    for (int o = 32; o; o >>= 1) s += __shfl_down(s, o);
    if ((t & 63) == 0) red[t >> 6] = s;
    __syncthreads();
    if (t == 0) out[0] = ((red[0] + red[1]) + (red[2] + red[3])) / (float)N_ROWS;
}

extern "C" void kernel_launch(void* const* d_in, const int* in_sizes, int n_in,
                              void* d_out, int out_size, void* d_ws, size_t ws_size,
                              hipStream_t stream) {
    const float* feats  = (const float*)d_in[0];
    const int*   labels = (const int*)d_in[1];
    float* out = (float*)d_out;

    char* ws = (char*)d_ws;
    ushort* fb    = (ushort*)ws;              ws += (size_t)N_ROWS * D_DIM * 2;      // 2 MiB
    float* pm     = (float*)ws;               ws += (size_t)NCHUNK * N_ROWS * 4;     // 512 KiB
    float* ps     = (float*)ws;               ws += (size_t)NCHUNK * N_ROWS * 4;     // 512 KiB
    int*   cls    = (int*)ws;                 ws += B_SAMP * 4;
    int*   count  = (int*)ws;                 ws += NCLS * 4;
    float* F      = (float*)ws;               ws += NCLS * D_DIM * 4;
    float* G      = (float*)ws;               ws += NCLS * D_DIM * 4;
    float* WmC    = (float*)ws;               ws += NCLS * 4;
    float* WC     = (float*)ws;               ws += NCLS * 4;
    float* gdiag  = (float*)ws;               ws += NCLS * 4;
    float* mdiag  = (float*)ws;               ws += NCLS * 4;
    float* partial= (float*)ws;               ws += 2048 * 4;

    k_zero    <<<1, 256, 0, stream>>>(F, count);
    k_castfeat<<<64, 256, 0, stream>>>(feats, labels, cls, count, F, fb);
    k_tables  <<<NCLS, 128, 0, stream>>>(F, count, G, WmC, WC, gdiag, mdiag);
    k_gemm3   <<<512, 256, 0, stream>>>(fb, pm, ps);
    k_final2  <<<2048, 256, 0, stream>>>(feats, cls, G, pm, ps, WmC, WC, gdiag, mdiag, partial);
    k_out     <<<1, 256, 0, stream>>>(partial, out);
}